// Round 3
// baseline (45.480 us; speedup 1.0000x reference)
//
#include <hip/hip_runtime.h>

// Reference collapses: softmax over a size-1 axis => l == 1, so
//   out[b, a, d] = sum_{t} value[a, b, t, d]
// Memory-bound fp32 reduction over 256 MiB.
// R3: contiguous-streaming blocks. Each pass-1 block owns a contiguous 1 MiB
// slab (one (a,b), one T-quarter, full D); 4 groups x 4 waves stream disjoint
// contiguous 256 KiB sub-ranges. Tiny ws partial (1 MiB) + fold pass.

constexpr int A_ = 4, B_ = 16, T_ = 1024, D_ = 1024;
constexpr int NQ   = 4;            // T-quarters per (a,b)
constexpr int QROW = T_ / NQ;      // 256 rows per block
constexpr int NG   = 4;            // groups per block (256 threads each)
constexpr int GROW = QROW / NG;    // 64 rows per group
constexpr int D4   = D_ / 4;       // 256 float4 per row

__global__ __launch_bounds__(1024) void wa_pass1(const float* __restrict__ value,
                                                 float* __restrict__ ws) {
    const int blk = blockIdx.x;            // 0 .. A*B*NQ-1
    const int q   = blk % NQ;
    const int ab  = blk / NQ;
    const int t4  = threadIdx.x & (D4 - 1);   // float4 index over D
    const int g   = threadIdx.x >> 8;         // group 0..3

    const float4* vp = reinterpret_cast<const float4*>(
        value + (size_t)ab * T_ * D_ + (size_t)(q * QROW + g * GROW) * D_) + t4;

    float4 a0{0.f,0.f,0.f,0.f}, a1{0.f,0.f,0.f,0.f};
    float4 a2{0.f,0.f,0.f,0.f}, a3{0.f,0.f,0.f,0.f};
    for (int r = 0; r < GROW; r += 4) {
        float4 v0 = vp[(size_t)(r + 0) * D4];
        float4 v1 = vp[(size_t)(r + 1) * D4];
        float4 v2 = vp[(size_t)(r + 2) * D4];
        float4 v3 = vp[(size_t)(r + 3) * D4];
        a0.x += v0.x; a0.y += v0.y; a0.z += v0.z; a0.w += v0.w;
        a1.x += v1.x; a1.y += v1.y; a1.z += v1.z; a1.w += v1.w;
        a2.x += v2.x; a2.y += v2.y; a2.z += v2.z; a2.w += v2.w;
        a3.x += v3.x; a3.y += v3.y; a3.z += v3.z; a3.w += v3.w;
    }
    float4 s;
    s.x = (a0.x + a1.x) + (a2.x + a3.x);
    s.y = (a0.y + a1.y) + (a2.y + a3.y);
    s.z = (a0.z + a1.z) + (a2.z + a3.z);
    s.w = (a0.w + a1.w) + (a2.w + a3.w);

    __shared__ float4 lds[NG * D4];        // 16 KiB
    lds[threadIdx.x] = s;
    __syncthreads();
    if (g < 2) {
        float4 o = lds[threadIdx.x + 2 * D4];
        float4 m = lds[threadIdx.x];
        m.x += o.x; m.y += o.y; m.z += o.z; m.w += o.w;
        lds[threadIdx.x] = m;
    }
    __syncthreads();
    if (g == 0) {
        float4 o = lds[t4 + D4];
        float4 m = lds[t4];
        m.x += o.x; m.y += o.y; m.z += o.z; m.w += o.w;
        reinterpret_cast<float4*>(ws + (size_t)blk * D_)[t4] = m;
    }
}

__global__ __launch_bounds__(256) void wa_pass2(const float* __restrict__ ws,
                                                float* __restrict__ out) {
    const int ab = blockIdx.x;             // 0 .. A*B-1
    const int a  = ab / B_;
    const int b  = ab % B_;
    const int t4 = threadIdx.x;
    float4 acc{0.f,0.f,0.f,0.f};
    #pragma unroll
    for (int q = 0; q < NQ; ++q) {
        float4 v = reinterpret_cast<const float4*>(ws + (size_t)(ab * NQ + q) * D_)[t4];
        acc.x += v.x; acc.y += v.y; acc.z += v.z; acc.w += v.w;
    }
    reinterpret_cast<float4*>(out + (size_t)(b * A_ + a) * D_)[t4] = acc;
}

// Fallback (ws too small): R2's fused kernel (D-chunked, no ws).
constexpr int NCH = 4, CHW = D_ / NCH, NGf = 16, GT = CHW / 4, ROWS = T_ / NGf;
__global__ __launch_bounds__(1024) void wa_fused(const float* __restrict__ value,
                                                 float* __restrict__ out) {
    const int blk = blockIdx.x;
    const int ch  = blk % NCH;
    const int ab  = blk / NCH;
    const int a   = ab / B_;
    const int b   = ab % B_;
    const int t   = threadIdx.x % GT;
    const int g   = threadIdx.x / GT;
    const float4* vp = reinterpret_cast<const float4*>(
        value + (size_t)ab * T_ * D_ + (size_t)g * ROWS * D_ + (size_t)ch * CHW) + t;
    float4 a0{0.f,0.f,0.f,0.f}, a1{0.f,0.f,0.f,0.f};
    float4 a2{0.f,0.f,0.f,0.f}, a3{0.f,0.f,0.f,0.f};
    for (int r = 0; r < ROWS; r += 4) {
        float4 v0 = vp[(size_t)(r + 0) * (D_ / 4)];
        float4 v1 = vp[(size_t)(r + 1) * (D_ / 4)];
        float4 v2 = vp[(size_t)(r + 2) * (D_ / 4)];
        float4 v3 = vp[(size_t)(r + 3) * (D_ / 4)];
        a0.x += v0.x; a0.y += v0.y; a0.z += v0.z; a0.w += v0.w;
        a1.x += v1.x; a1.y += v1.y; a1.z += v1.z; a1.w += v1.w;
        a2.x += v2.x; a2.y += v2.y; a2.z += v2.z; a2.w += v2.w;
        a3.x += v3.x; a3.y += v3.y; a3.z += v3.z; a3.w += v3.w;
    }
    float4 s;
    s.x = (a0.x + a1.x) + (a2.x + a3.x);
    s.y = (a0.y + a1.y) + (a2.y + a3.y);
    s.z = (a0.z + a1.z) + (a2.z + a3.z);
    s.w = (a0.w + a1.w) + (a2.w + a3.w);
    __shared__ float4 lds[NGf * GT];
    lds[g * GT + t] = s;
    __syncthreads();
    #pragma unroll
    for (int sg = NGf / 2; sg >= 1; sg >>= 1) {
        if (g < sg) {
            float4 o = lds[(g + sg) * GT + t];
            float4 m = lds[g * GT + t];
            m.x += o.x; m.y += o.y; m.z += o.z; m.w += o.w;
            lds[g * GT + t] = m;
        }
        __syncthreads();
    }
    if (g == 0)
        reinterpret_cast<float4*>(out + (size_t)(b * A_ + a) * D_ + (size_t)ch * CHW)[t] = lds[t];
}

extern "C" void kernel_launch(void* const* d_in, const int* in_sizes, int n_in,
                              void* d_out, int out_size, void* d_ws, size_t ws_size,
                              hipStream_t stream) {
    const float* value = (const float*)d_in[1];   // (A, B, T, D) fp32
    float* out = (float*)d_out;                   // (B, A, D) fp32
    const size_t need = (size_t)A_ * B_ * NQ * D_ * sizeof(float);  // 1 MiB
    if (ws_size >= need) {
        float* ws = (float*)d_ws;
        wa_pass1<<<A_ * B_ * NQ, 1024, 0, stream>>>(value, ws);
        wa_pass2<<<A_ * B_, 256, 0, stream>>>(ws, out);
    } else {
        wa_fused<<<A_ * B_ * NCH, 1024, 0, stream>>>(value, out);
    }
}

// Round 4
// 42.893 us; speedup vs baseline: 1.0603x; 1.0603x over previous
//
#include <hip/hip_runtime.h>

// Reference collapses: softmax over a size-1 axis => l == 1 everywhere, so
//   out[b, a, d] = sum_{t=0}^{T-1} value[a, b, t, d]
// Pure memory-bound fp32 reduction over 256 MiB. Single fused kernel
// (measured best: 43.06 us = 6.24 TB/s = 99% of the 6.29 TB/s read ceiling).
// grid = A*B*4 blocks; each block owns one (a,b, 256-float D-stripe);
// 16 t-groups x 64 lanes sum 64 rows each; LDS tree folds the 16 partials.
// R3's contiguous-slab variant measured SLOWER (45.5 us) — keep D-chunked.

constexpr int A_ = 4, B_ = 16, T_ = 1024, D_ = 1024;
constexpr int NCH  = 4;           // D-chunks per (a,b)
constexpr int CHW  = D_ / NCH;    // 256 floats per chunk (= 1 KiB = one wave's float4)
constexpr int NG   = 16;          // t-groups per block
constexpr int GT   = CHW / 4;     // 64 threads per group (float4 each)
constexpr int ROWS = T_ / NG;     // 64 rows per group
constexpr int STRIDE4 = D_ / 4;   // float4 stride between consecutive t

__global__ __launch_bounds__(1024) void wa_fused(const float* __restrict__ value,
                                                 float* __restrict__ out) {
    const int blk = blockIdx.x;            // 0 .. A*B*NCH-1
    const int ch  = blk % NCH;
    const int ab  = blk / NCH;
    const int a   = ab / B_;
    const int b   = ab % B_;
    const int t   = threadIdx.x % GT;      // lane within group (d index)
    const int g   = threadIdx.x / GT;      // t-group 0..15

    const float4* vp = reinterpret_cast<const float4*>(
        value + (size_t)ab * T_ * D_ + (size_t)g * ROWS * D_ + (size_t)ch * CHW) + t;

    float4 a0{0.f,0.f,0.f,0.f}, a1{0.f,0.f,0.f,0.f};
    float4 a2{0.f,0.f,0.f,0.f}, a3{0.f,0.f,0.f,0.f};
    for (int r = 0; r < ROWS; r += 4) {
        float4 v0 = vp[(size_t)(r + 0) * STRIDE4];
        float4 v1 = vp[(size_t)(r + 1) * STRIDE4];
        float4 v2 = vp[(size_t)(r + 2) * STRIDE4];
        float4 v3 = vp[(size_t)(r + 3) * STRIDE4];
        a0.x += v0.x; a0.y += v0.y; a0.z += v0.z; a0.w += v0.w;
        a1.x += v1.x; a1.y += v1.y; a1.z += v1.z; a1.w += v1.w;
        a2.x += v2.x; a2.y += v2.y; a2.z += v2.z; a2.w += v2.w;
        a3.x += v3.x; a3.y += v3.y; a3.z += v3.z; a3.w += v3.w;
    }
    float4 s;
    s.x = (a0.x + a1.x) + (a2.x + a3.x);
    s.y = (a0.y + a1.y) + (a2.y + a3.y);
    s.z = (a0.z + a1.z) + (a2.z + a3.z);
    s.w = (a0.w + a1.w) + (a2.w + a3.w);

    __shared__ float4 lds[NG * GT];        // 16 KiB
    lds[g * GT + t] = s;
    __syncthreads();
    #pragma unroll
    for (int sg = NG / 2; sg >= 1; sg >>= 1) {
        if (g < sg) {
            float4 o = lds[(g + sg) * GT + t];
            float4 m = lds[g * GT + t];
            m.x += o.x; m.y += o.y; m.z += o.z; m.w += o.w;
            lds[g * GT + t] = m;
        }
        __syncthreads();
    }
    if (g == 0) {
        reinterpret_cast<float4*>(
            out + ((size_t)(b * A_ + a)) * D_ + (size_t)ch * CHW)[t] = lds[t];
    }
}

extern "C" void kernel_launch(void* const* d_in, const int* in_sizes, int n_in,
                              void* d_out, int out_size, void* d_ws, size_t ws_size,
                              hipStream_t stream) {
    const float* value = (const float*)d_in[1];   // (A, B, T, D) fp32
    float* out = (float*)d_out;                   // (B, A, D) fp32
    wa_fused<<<A_ * B_ * NCH, 1024, 0, stream>>>(value, out);
}